// Round 5
// baseline (40.139 us; speedup 1.0000x reference)
//
#include <hip/hip_runtime.h>
#include <math.h>

namespace {
constexpr int kNB  = 16;
constexpr int kNF  = 512;
constexpr int kNTS = 2048;
constexpr int kTPB = 256;
constexpr int kEPT = kNTS / kTPB;   // 8 elements per thread
constexpr int kVPT = kEPT / 4;      // 2 float4 loads per array
constexpr int kPPT = kEPT / 2;      // 4 packed float2 pairs per thread
// 1/(8*pi^2) rounded to fp32
constexpr float kC     = 0.012665147955292222f;
constexpr float kTwoPi = 6.28318530717958647692f;

constexpr float kTwoOverPi = 0.636619772367581343f;
constexpr float kP1 = 1.5703125f;               // 201 * 2^-7
constexpr float kP2 = 4.84466552734375e-4f;     // 127 * 2^-18
constexpr float kP3 = -6.407499313354492e-7f;   // -86 * 2^-27
constexpr float kP4 = 9.895302355289459e-10f;   //  68 * 2^-36
}

// Packed fp32: 2 elements/lane/issue-slot via v_pk_fma_f32 / v_pk_mul_f32 on CDNA.
typedef float vf2 __attribute__((ext_vector_type(2)));

__device__ __forceinline__ vf2 v2(float a) { return (vf2){a, a}; }
__device__ __forceinline__ vf2 vfma(vf2 a, vf2 b, vf2 c) {
  return __builtin_elementwise_fma(a, b, c);
}

// Scalar quadrant fixup (cndmask/xor — not packable, cheap). Returns by value.
__device__ __forceinline__ float quad_fix_s(float s, float c, int q) {
  float ss = ((q & 1) != 0) ? c : s;
  unsigned sgn = (unsigned)(q & 2) << 30;
  return __uint_as_float(__float_as_uint(ss) ^ sgn);
}
__device__ __forceinline__ float quad_fix_c(float s, float c, int q) {
  float cc = ((q & 1) != 0) ? s : c;
  unsigned sgn = (unsigned)((q + 1) & 2) << 30;
  return __uint_as_float(__float_as_uint(cc) ^ sgn);
}

// Branchless packed sincos for |x| < 2^17 (args bounded by ~1.3e5).
// fp32 Cody-Waite mod pi/2 (7-bit chunks, k*ci exact for k<2^17) + Cephes
// minimax polys, all in packed fp32. Per-element rounding is IEEE-identical
// to the scalar version (error ~4e-7 abs).
__device__ __forceinline__ void fast_sincosf2(vf2 x, vf2& s_out, vf2& c_out) {
  vf2 xk = x * v2(kTwoOverPi);
  float kfx = rintf(xk.x);
  float kfy = rintf(xk.y);
  int qx = (int)kfx;
  int qy = (int)kfy;
  vf2 nkf = (vf2){-kfx, -kfy};
  vf2 kf  = (vf2){kfx, kfy};
  (void)kf;
  vf2 r = vfma(nkf, v2(kP1), x);
  r = vfma(nkf, v2(kP2), r);
  r = vfma(nkf, v2(kP3), r);
  r = vfma(nkf, v2(kP4), r);

  vf2 z = r * r;
  vf2 sp = vfma(vfma(v2(-1.9515295891e-4f), z, v2(8.3321608736e-3f)), z,
                v2(-1.6666654611e-1f));
  vf2 s = vfma(sp * z, r, r);
  vf2 cp = vfma(vfma(v2(2.443315711809948e-5f), z, v2(-1.388731625493765e-3f)), z,
                v2(4.166664568298827e-2f));
  vf2 c = vfma(cp, z * z, vfma(v2(-0.5f), z, v2(1.0f)));

  float sx = quad_fix_s(s.x, c.x, qx);
  float cx = quad_fix_c(s.x, c.x, qx);
  float sy = quad_fix_s(s.y, c.y, qy);
  float cy = quad_fix_c(s.y, c.y, qy);
  s_out = (vf2){sx, sy};
  c_out = (vf2){cx, cy};
}

__launch_bounds__(kTPB)
__global__ void wavelet_ls_kernel(const float* __restrict__ ys,
                                  const float* __restrict__ ts,
                                  const float* __restrict__ freq,
                                  float* __restrict__ out) {
  const int f    = blockIdx.x;   // frequency index
  const int b    = blockIdx.y;   // batch index
  const int tid  = threadIdx.x;
  const int wave = tid >> 6;

  const float* __restrict__ tsb = ts + b * kNTS;
  const float* __restrict__ ysb = ys + b * kNTS;
  const float4* __restrict__ ts4 = (const float4*)tsb;
  const float4* __restrict__ ys4 = (const float4*)ysb;

  const float tau   = 0.5f * (tsb[kNTS / 2] + tsb[kNTS / 2 + 1]);
  const float omega = freq[f] * kTwoPi;

  // Per-thread sample state (pairs) kept in registers across both passes.
  vf2 tv[kPPT], yv[kPPT], wv[kPPT];

#pragma unroll
  for (int v = 0; v < kVPT; ++v) {
    const int vidx = v * kTPB + tid;      // coalesced float4
    const float4 t4 = ts4[vidx];
    const float4 y4 = ys4[vidx];
    tv[v * 2 + 0] = (vf2){t4.x, t4.y};
    tv[v * 2 + 1] = (vf2){t4.z, t4.w};
    yv[v * 2 + 0] = (vf2){y4.x, y4.y};
    yv[v * 2 + 1] = (vf2){y4.z, y4.w};
  }

  // Pass-1 accumulators (6): sum_w, w*sin, w*cos, w*(sin*cos), w*(cos^2-sin^2), w*y
  // (cos^2-sin^2 as 1-2*sin^2: ~3e-7/elem deviation -> uniform (a1,a2) rotation
  //  <= ~3e-4 in phase. Safe.)
  vf2 acc[6];
#pragma unroll
  for (int i = 0; i < 6; ++i) acc[i] = v2(0.0f);

#pragma unroll
  for (int p = 0; p < kPPT; ++p) {
    const vf2 t = tv[p];
    const vf2 y = yv[p];
    const vf2 dz = v2(omega) * (t - v2(tau));   // same rounding structure as ref
    const vf2 e  = (v2(-kC) * dz) * dz;
    vf2 w;
    float wx = __expf(e.x);
    float wy = __expf(e.y);
    w = (vf2){wx, wy};
    wv[p] = w;
    vf2 sn, cs;
    fast_sincosf2(v2(omega) * t, sn, cs);
    const vf2 c2 = vfma(v2(-2.0f) * sn, sn, v2(1.0f));   // cos^2 - sin^2
    acc[0] = acc[0] + w;
    acc[1] = vfma(w, sn, acc[1]);
    acc[2] = vfma(w, cs, acc[2]);
    acc[3] = vfma(w, sn * cs, acc[3]);
    acc[4] = vfma(w, c2, acc[4]);
    acc[5] = vfma(w, y, acc[5]);
  }

  // Horizontal add of the pair, butterfly within wave, combine 4 waves via LDS.
  __shared__ float lds1[4][6];
#pragma unroll
  for (int i = 0; i < 6; ++i) {
    float v = acc[i].x + acc[i].y;
#pragma unroll
    for (int off = 1; off < 64; off <<= 1) v += __shfl_xor(v, off, 64);
    if ((tid & 63) == 0) lds1[wave][i] = v;
  }
  __syncthreads();

  float tot[6];
#pragma unroll
  for (int i = 0; i < 6; ++i)
    tot[i] = (lds1[0][i] + lds1[1][i]) + (lds1[2][i] + lds1[3][i]);

  const float sum_w   = tot[0];
  const float inv_w   = 1.0f / sum_w;
  const float sin_one = tot[1] * inv_w;
  const float cos_one = tot[2] * inv_w;
  const float sin_cos = tot[3] * inv_w;
  const float cc_ss   = tot[4] * inv_w;    // cos_cos - sin_sin
  const float ys_one  = tot[5] * inv_w;

  const float num = 2.0f * (sin_cos - sin_one * cos_one);
  const float den = cc_ss - cos_one * cos_one + sin_one * sin_one;
  const float time_shift = atan2f(num, den) / (2.0f * omega);

  // Pass 2: recompute sincos(omega*(t - time_shift)) -- same fp32 rounding path
  // as ref. (Angle-subtraction identity forbidden: ~0.008 rad/elem argument
  // deviation would corrupt phase at small-amplitude bins.)
  vf2 acc2[4];
#pragma unroll
  for (int i = 0; i < 4; ++i) acc2[i] = v2(0.0f);

#pragma unroll
  for (int p = 0; p < kPPT; ++p) {
    vf2 sn, cs;
    fast_sincosf2(v2(omega) * (tv[p] - v2(time_shift)), sn, cs);
    const vf2 w = wv[p];
    acc2[0] = vfma(w, cs, acc2[0]);             // -> cos_shift_one
    acc2[1] = vfma(w, sn, acc2[1]);             // -> sin_shift_one
    acc2[2] = vfma(w, yv[p] * cs, acc2[2]);     // -> ys_cos_shift
    acc2[3] = vfma(w, yv[p] * sn, acc2[3]);     // -> ys_sin_shift
  }

  __shared__ float lds2[4][4];
#pragma unroll
  for (int i = 0; i < 4; ++i) {
    float v = acc2[i].x + acc2[i].y;
#pragma unroll
    for (int off = 1; off < 64; off <<= 1) v += __shfl_xor(v, off, 64);
    if ((tid & 63) == 0) lds2[wave][i] = v;
  }
  __syncthreads();

  if (tid == 0) {
    float t2[4];
#pragma unroll
    for (int i = 0; i < 4; ++i)
      t2[i] = (lds2[0][i] + lds2[1][i]) + (lds2[2][i] + lds2[3][i]);

    const float cos_shift_one = t2[0] * inv_w;
    const float sin_shift_one = t2[1] * inv_w;
    const float ys_cos_shift  = t2[2] * inv_w;
    const float ys_sin_shift  = t2[3] * inv_w;

    float stc, ctc;
    sincosf(omega * (time_shift - tau), &stc, &ctc);  // once per block: keep libm

    const float A  = 2.0f * (ys_cos_shift - ys_one * cos_shift_one);
    const float B  = 2.0f * (ys_sin_shift - ys_one * sin_shift_one);
    const float a0 = ys_one;
    const float a1 = ctc * A - stc * B;
    const float a2 = stc * A + ctc * B;
    const float wwp   = a1 * a1 + a2 * a2;
    const float phase = atan2f(a2, a1);

    const int o = b * kNF + f;
    out[0 * kNB * kNF + o] = wwp;
    out[1 * kNB * kNF + o] = phase;
    out[2 * kNB * kNF + o] = a0;
    out[3 * kNB * kNF + o] = a1;
    out[4 * kNB * kNF + o] = a2;
  }
}

extern "C" void kernel_launch(void* const* d_in, const int* in_sizes, int n_in,
                              void* d_out, int out_size, void* d_ws, size_t ws_size,
                              hipStream_t stream) {
  const float* ys   = (const float*)d_in[0];
  const float* ts   = (const float*)d_in[1];
  const float* freq = (const float*)d_in[2];
  float* out = (float*)d_out;

  dim3 grid(kNF, kNB);
  wavelet_ls_kernel<<<grid, kTPB, 0, stream>>>(ys, ts, freq, out);
}